// Round 1
// baseline (4208.163 us; speedup 1.0000x reference)
//
#include <hip/hip_runtime.h>
#include <hip/hip_bf16.h>
#include <math.h>

#define S_LEN  2048
#define DMODEL 2560
#define NHEADS 32
#define NKV    8
#define HD     128
#define QKDIM  (NHEADS * HD)   // 4096
#define KVDIM  (NKV * HD)      // 1024

// ---------------------------------------------------------------------------
// Generic NT GEMM: C[M][N] = A[M][K] * B[N][K]^T   (both row-major, dot rows)
// 64x64 C tile per 256-thread block, 4x4 micro-tile per thread, BK=16.
// All shapes used are divisible by 64 (M,N) and 16 (K); no bounds checks.
// ---------------------------------------------------------------------------
__global__ __launch_bounds__(256) void gemm_nt(const float* __restrict__ A,
                                               const float* __restrict__ B,
                                               float* __restrict__ C,
                                               int M, int N, int K) {
    __shared__ float As[64][17];
    __shared__ float Bs[64][17];
    const int tid = threadIdx.x;
    const int tx = tid & 15;        // 0..15  -> C cols tx*4..tx*4+3
    const int ty = tid >> 4;        // 0..15  -> C rows ty*4..ty*4+3
    const int m0 = blockIdx.y * 64;
    const int n0 = blockIdx.x * 64;
    const int lrow = tid >> 2;      // 0..63
    const int lcol = (tid & 3) << 2;// 0,4,8,12

    float acc[4][4] = {};
    for (int k0 = 0; k0 < K; k0 += 16) {
        float4 av = *(const float4*)(A + (size_t)(m0 + lrow) * K + k0 + lcol);
        float4 bv = *(const float4*)(B + (size_t)(n0 + lrow) * K + k0 + lcol);
        As[lrow][lcol]   = av.x; As[lrow][lcol+1] = av.y;
        As[lrow][lcol+2] = av.z; As[lrow][lcol+3] = av.w;
        Bs[lrow][lcol]   = bv.x; Bs[lrow][lcol+1] = bv.y;
        Bs[lrow][lcol+2] = bv.z; Bs[lrow][lcol+3] = bv.w;
        __syncthreads();
#pragma unroll
        for (int k = 0; k < 16; ++k) {
            float a[4], b[4];
#pragma unroll
            for (int i = 0; i < 4; ++i) a[i] = As[ty*4+i][k];
#pragma unroll
            for (int j = 0; j < 4; ++j) b[j] = Bs[tx*4+j][k];
#pragma unroll
            for (int i = 0; i < 4; ++i)
#pragma unroll
                for (int j = 0; j < 4; ++j)
                    acc[i][j] = fmaf(a[i], b[j], acc[i][j]);
        }
        __syncthreads();
    }
#pragma unroll
    for (int i = 0; i < 4; ++i)
#pragma unroll
        for (int j = 0; j < 4; ++j)
            C[(size_t)(m0 + ty*4 + i) * N + n0 + tx*4 + j] = acc[i][j];
}

// ---------------------------------------------------------------------------
// Per-(s, head) RMSNorm + RoPE.  Grid: (40, 2048); slot 0..31 = Q head,
// slot 32..39 = KV head (also copies V into the cache layout).
// Q output is pre-scaled by 1/sqrt(HD) and transposed to [h][s][d].
// K output goes straight into d_out's cache_k region [g][s][d] (no scale).
// ---------------------------------------------------------------------------
__global__ __launch_bounds__(128) void norm_rope(const float* __restrict__ qg,
                                                 const float* __restrict__ kg,
                                                 const float* __restrict__ vg,
                                                 const float* __restrict__ qw,
                                                 const float* __restrict__ kw,
                                                 float* __restrict__ qr,
                                                 float* __restrict__ kc,
                                                 float* __restrict__ vc) {
    const int slot = blockIdx.x;   // 0..39
    const int s    = blockIdx.y;   // 0..2047
    const int d    = threadIdx.x;  // 0..127

    float x;
    const float* w;
    if (slot < NHEADS) {
        x = qg[(size_t)s * QKDIM + slot * HD + d];
        w = qw;
    } else {
        const int g = slot - NHEADS;
        x = kg[(size_t)s * KVDIM + g * HD + d];
        w = kw;
        vc[((size_t)g * S_LEN + s) * HD + d] = vg[(size_t)s * KVDIM + g * HD + d];
    }

    // block-wide mean of squares over 128 lanes (2 waves)
    float ssum = x * x;
#pragma unroll
    for (int off = 1; off < 64; off <<= 1) ssum += __shfl_xor(ssum, off);
    __shared__ float red[2];
    __shared__ float ynorm[128];
    if ((d & 63) == 0) red[d >> 6] = ssum;
    __syncthreads();
    const float mean = (red[0] + red[1]) * (1.0f / 128.0f);
    const float y = x * rsqrtf(mean + 1e-6f) * w[d];
    ynorm[d] = y;
    __syncthreads();
    const float partner = ynorm[d ^ 64];

    // RoPE (NeoX halves). Double-precision angle: pos up to 2047 amplifies
    // inv_freq rounding; keep phase error negligible.
    const int i = d & 63;
    const double invf = pow(5.0e6, -(double)i / 64.0);
    const double ang = (double)s * invf;
    const float cs = (float)cos(ang);
    const float sn = (float)sin(ang);
    const float outv = (d < 64) ? (y * cs - partner * sn)
                                : (y * cs + partner * sn);

    if (slot < NHEADS) {
        // fold attention scale 1/sqrt(128) into Q
        qr[((size_t)slot * S_LEN + s) * HD + d] = outv * 0.08838834764831845f;
    } else {
        kc[((size_t)(slot - NHEADS) * S_LEN + s) * HD + d] = outv;
    }
}

// ---------------------------------------------------------------------------
// Flash-style causal attention.  Block = 256 threads, handles one head and a
// 32-query tile; iterates over 64-key tiles with online softmax.
// Q pre-scaled by 1/sqrt(HD).  Output written as [s][h*HD+d] for the Wo GEMM.
// LDS: Qs 32x129 + KVs 64x129 (K then V reuse) + Ps 32x65 = ~57.9 KB.
// ---------------------------------------------------------------------------
__global__ __launch_bounds__(256) void attn_fwd(const float* __restrict__ Q,
                                                const float* __restrict__ Kc,
                                                const float* __restrict__ Vc,
                                                float* __restrict__ O) {
    __shared__ float Qs[32][129];
    __shared__ float KVs[64][129];
    __shared__ float Ps[32][65];

    const int h  = blockIdx.y;        // 0..31
    const int g  = h >> 2;            // kv group
    const int q0 = blockIdx.x * 32;   // first query row
    const int tid = threadIdx.x;
    const int tx = tid & 31;          // 0..31
    const int ty = tid >> 5;          // 0..7 -> rows ty*4..ty*4+3

    // stage Q tile (32x128)
    const float* Qbase = Q + ((size_t)h * S_LEN + q0) * HD;
    for (int e = tid; e < 32 * 32; e += 256) {
        const int r = e >> 5, c = (e & 31) << 2;
        float4 v = *(const float4*)(Qbase + r * HD + c);
        Qs[r][c] = v.x; Qs[r][c+1] = v.y; Qs[r][c+2] = v.z; Qs[r][c+3] = v.w;
    }

    float m_i[4], l_i[4], o_acc[4][4];
#pragma unroll
    for (int i = 0; i < 4; ++i) {
        m_i[i] = -INFINITY; l_i[i] = 0.0f;
#pragma unroll
        for (int j = 0; j < 4; ++j) o_acc[i][j] = 0.0f;
    }

    const int kt_max = (q0 + 31) >> 6;   // inclusive
    for (int kt = 0; kt <= kt_max; ++kt) {
        __syncthreads();   // everyone done with previous V before overwrite
        // stage K tile (64x128)
        const float* Kbase = Kc + ((size_t)g * S_LEN + kt * 64) * HD;
        for (int e = tid; e < 64 * 32; e += 256) {
            const int r = e >> 5, c = (e & 31) << 2;
            float4 v = *(const float4*)(Kbase + r * HD + c);
            KVs[r][c] = v.x; KVs[r][c+1] = v.y; KVs[r][c+2] = v.z; KVs[r][c+3] = v.w;
        }
        __syncthreads();

        // QK^T: thread computes rows ty*4+i, cols tx*2+j
        float sc[4][2] = {};
#pragma unroll 4
        for (int d = 0; d < HD; ++d) {
            float a[4], b[2];
#pragma unroll
            for (int i = 0; i < 4; ++i) a[i] = Qs[ty*4+i][d];
            b[0] = KVs[tx*2][d]; b[1] = KVs[tx*2+1][d];
#pragma unroll
            for (int i = 0; i < 4; ++i) {
                sc[i][0] = fmaf(a[i], b[0], sc[i][0]);
                sc[i][1] = fmaf(a[i], b[1], sc[i][1]);
            }
        }

        // causal mask + online softmax per row
#pragma unroll
        for (int i = 0; i < 4; ++i) {
            const int row_g = q0 + ty*4 + i;
#pragma unroll
            for (int j = 0; j < 2; ++j) {
                const int col_g = kt*64 + tx*2 + j;
                if (col_g > row_g) sc[i][j] = -INFINITY;
            }
            float rowmax = fmaxf(sc[i][0], sc[i][1]);
#pragma unroll
            for (int off = 16; off; off >>= 1)
                rowmax = fmaxf(rowmax, __shfl_xor(rowmax, off));
            const float m_new = fmaxf(m_i[i], rowmax);
            const float alpha = expf(m_i[i] - m_new);   // 0 when m_i=-inf
            const float p0 = expf(sc[i][0] - m_new);    // 0 when masked
            const float p1 = expf(sc[i][1] - m_new);
            float psum = p0 + p1;
#pragma unroll
            for (int off = 16; off; off >>= 1)
                psum += __shfl_xor(psum, off);
            l_i[i] = l_i[i] * alpha + psum;
            m_i[i] = m_new;
#pragma unroll
            for (int j = 0; j < 4; ++j) o_acc[i][j] *= alpha;
            Ps[ty*4+i][tx*2]   = p0;
            Ps[ty*4+i][tx*2+1] = p1;
        }
        __syncthreads();   // P visible; everyone done reading K

        // stage V tile into the same buffer
        const float* Vbase = Vc + ((size_t)g * S_LEN + kt * 64) * HD;
        for (int e = tid; e < 64 * 32; e += 256) {
            const int r = e >> 5, c = (e & 31) << 2;
            float4 v = *(const float4*)(Vbase + r * HD + c);
            KVs[r][c] = v.x; KVs[r][c+1] = v.y; KVs[r][c+2] = v.z; KVs[r][c+3] = v.w;
        }
        __syncthreads();

        // PV: thread accumulates rows ty*4+i, cols tx*4+j
#pragma unroll 2
        for (int kk = 0; kk < 64; ++kk) {
            float p[4], v[4];
#pragma unroll
            for (int i = 0; i < 4; ++i) p[i] = Ps[ty*4+i][kk];
#pragma unroll
            for (int j = 0; j < 4; ++j) v[j] = KVs[kk][tx*4+j];
#pragma unroll
            for (int i = 0; i < 4; ++i)
#pragma unroll
                for (int j = 0; j < 4; ++j)
                    o_acc[i][j] = fmaf(p[i], v[j], o_acc[i][j]);
        }
    }

    // epilogue: normalize and write [s][h*HD + d]
#pragma unroll
    for (int i = 0; i < 4; ++i) {
        const float inv_l = 1.0f / l_i[i];
        const int s = q0 + ty*4 + i;
#pragma unroll
        for (int j = 0; j < 4; ++j)
            O[(size_t)s * QKDIM + h * HD + tx*4 + j] = o_acc[i][j] * inv_l;
    }
}

// ---------------------------------------------------------------------------
extern "C" void kernel_launch(void* const* d_in, const int* in_sizes, int n_in,
                              void* d_out, int out_size, void* d_ws, size_t ws_size,
                              hipStream_t stream) {
    const float* x  = (const float*)d_in[0];   // [2048][2560]
    const float* Wq = (const float*)d_in[1];   // [4096][2560]
    const float* Wk = (const float*)d_in[2];   // [1024][2560]
    const float* Wv = (const float*)d_in[3];   // [1024][2560]
    const float* Wo = (const float*)d_in[4];   // [2560][4096]
    const float* qw = (const float*)d_in[5];   // [128]
    const float* kw = (const float*)d_in[6];   // [128]

    float* out     = (float*)d_out;                         // [2048][2560]
    float* cache_k = out + (size_t)S_LEN * DMODEL;          // [8][2048][128]
    float* cache_v = cache_k + (size_t)NKV * S_LEN * HD;    // [8][2048][128]

    float* ws = (float*)d_ws;
    float* qg = ws;                                   // [2048][4096]
    float* kg = qg + (size_t)S_LEN * QKDIM;           // [2048][1024]
    float* vg = kg + (size_t)S_LEN * KVDIM;           // [2048][1024]
    float* qr = vg + (size_t)S_LEN * KVDIM;           // [32][2048][128]
    float* ao = qg;  // reuse: qg dead after norm_rope // [2048][4096]

    // 1) QKV projections
    gemm_nt<<<dim3(QKDIM/64, S_LEN/64), 256, 0, stream>>>(x, Wq, qg, S_LEN, QKDIM, DMODEL);
    gemm_nt<<<dim3(KVDIM/64, S_LEN/64), 256, 0, stream>>>(x, Wk, kg, S_LEN, KVDIM, DMODEL);
    gemm_nt<<<dim3(KVDIM/64, S_LEN/64), 256, 0, stream>>>(x, Wv, vg, S_LEN, KVDIM, DMODEL);

    // 2) RMSNorm + RoPE (+ V transpose into cache)
    norm_rope<<<dim3(NHEADS + NKV, S_LEN), 128, 0, stream>>>(qg, kg, vg, qw, kw,
                                                             qr, cache_k, cache_v);

    // 3) causal GQA attention
    attn_fwd<<<dim3(S_LEN/32, NHEADS), 256, 0, stream>>>(qr, cache_k, cache_v, ao);

    // 4) output projection
    gemm_nt<<<dim3(DMODEL/64, S_LEN/64), 256, 0, stream>>>(ao, Wo, out, S_LEN, DMODEL, QKDIM);
}

// Round 2
// 2396.909 us; speedup vs baseline: 1.7557x; 1.7557x over previous
//
#include <hip/hip_runtime.h>
#include <hip/hip_bf16.h>
#include <math.h>

#define S_LEN  2048
#define DMODEL 2560
#define NHEADS 32
#define NKV    8
#define HD     128
#define QKDIM  (NHEADS * HD)   // 4096
#define KVDIM  (NKV * HD)      // 1024

typedef __bf16 bf16x8 __attribute__((ext_vector_type(8)));
typedef float  f32x4  __attribute__((ext_vector_type(4)));
typedef unsigned short u16;

#define AS1 __attribute__((address_space(1)))
#define AS3 __attribute__((address_space(3)))

__device__ __forceinline__ void load16_to_lds(const void* g, void* l) {
    __builtin_amdgcn_global_load_lds((const AS1 void*)g, (AS3 void*)l, 16, 0, 0);
}

__device__ __forceinline__ u16 f2bf(float f) {
    unsigned u = __builtin_bit_cast(unsigned, f);
    return (u16)((u + 0x7fff + ((u >> 16) & 1)) >> 16);   // RTNE
}

// ---------------------------------------------------------------------------
// fp32 -> bf16 convert, 4 elements/thread, grid-stride. n4 = n/4.
// ---------------------------------------------------------------------------
__global__ __launch_bounds__(256) void f32_to_bf16_k(const float* __restrict__ in,
                                                     u16* __restrict__ out, int n4) {
    int i = blockIdx.x * 256 + threadIdx.x;
    const int stride = gridDim.x * 256;
    for (; i < n4; i += stride) {
        float4 v = ((const float4*)in)[i];
        ushort4 r;
        r.x = f2bf(v.x); r.y = f2bf(v.y); r.z = f2bf(v.z); r.w = f2bf(v.w);
        ((ushort4*)out)[i] = r;
    }
}

// ---------------------------------------------------------------------------
// bf16 MFMA NT GEMM (m97 pattern): C[M][N] = A[M][K] * B[N][K]^T, C fp32.
// Block = 256 threads (4 waves), 128x128 C tile, BK=32 (one mfma k-step).
// Wave w -> 64x64 quadrant (wm=w>>1, wn=w&1), 4x4 grid of 16x16 MFMA tiles.
// LDS layout = fragment-chunk order: chunk c (16 B = 8 bf16) holds
//   T[(c>>6)*16 + (c&15)][ ((c&63)>>4)*8 .. +7 ]   (T = A or B tile, k-minor)
// so global_load_lds (wave-uniform base + lane*16) lands each lane's chunk
// exactly where that lane's ds_read_b128 fragment read expects it.
// M%128==0, N%128==0, K%32==0 for all four calls — no bounds checks.
// ---------------------------------------------------------------------------
__global__ __launch_bounds__(256) void gemm_bf16_nt(const __bf16* __restrict__ A,
                                                    const __bf16* __restrict__ B,
                                                    float* __restrict__ C,
                                                    int M, int N, int K) {
    __shared__ __align__(16) __bf16 Als[128 * 32];
    __shared__ __align__(16) __bf16 Bls[128 * 32];
    const int tid  = threadIdx.x;
    const int lane = tid & 63;
    const int wave = tid >> 6;
    const int wm   = wave >> 1, wn = wave & 1;
    const int m0   = blockIdx.y * 128;
    const int n0   = blockIdx.x * 128;
    const int frow = lane & 15;   // row within 16-row group
    const int fkq  = lane >> 4;   // k-quad (8 bf16 each)

    f32x4 acc[4][4];
#pragma unroll
    for (int t = 0; t < 4; ++t)
#pragma unroll
        for (int u = 0; u < 4; ++u)
            acc[t][u] = (f32x4){0.f, 0.f, 0.f, 0.f};

    for (int k0 = 0; k0 < K; k0 += 32) {
        __syncthreads();                       // prev iter's ds_reads done
#pragma unroll
        for (int i = 0; i < 2; ++i) {
            const int mt  = i * 4 + wave;      // 16-row group 0..7
            const int row = mt * 16 + frow;
            const int col = k0 + fkq * 8;
            __bf16* ldsA = &Als[(size_t)(i * 256 + wave * 64) * 8]; // wave-uniform
            __bf16* ldsB = &Bls[(size_t)(i * 256 + wave * 64) * 8];
            load16_to_lds(A + (size_t)(m0 + row) * K + col, ldsA);
            load16_to_lds(B + (size_t)(n0 + row) * K + col, ldsB);
        }
        __syncthreads();                       // drains vmcnt (compiler-emitted)

        bf16x8 af[4], bfr[4];
#pragma unroll
        for (int t = 0; t < 4; ++t)
            af[t]  = *(const bf16x8*)&Als[((wm * 4 + t) * 64 + lane) * 8];
#pragma unroll
        for (int u = 0; u < 4; ++u)
            bfr[u] = *(const bf16x8*)&Bls[((wn * 4 + u) * 64 + lane) * 8];
#pragma unroll
        for (int t = 0; t < 4; ++t)
#pragma unroll
            for (int u = 0; u < 4; ++u)
                acc[t][u] = __builtin_amdgcn_mfma_f32_16x16x32_bf16(
                                af[t], bfr[u], acc[t][u], 0, 0, 0);
    }

    // C/D layout: col = lane&15, row = (lane>>4)*4 + r   [m89/m91 verified]
    const int crow = (lane >> 4) * 4;
    const int ccol = lane & 15;
#pragma unroll
    for (int t = 0; t < 4; ++t) {
        const int gr = m0 + (wm * 4 + t) * 16 + crow;
#pragma unroll
        for (int u = 0; u < 4; ++u) {
            const int gc = n0 + (wn * 4 + u) * 16 + ccol;
#pragma unroll
            for (int r = 0; r < 4; ++r)
                C[(size_t)(gr + r) * N + gc] = acc[t][u][r];
        }
    }
}

// ---------------------------------------------------------------------------
// Per-(s, head) RMSNorm + RoPE (unchanged from round 1).
// ---------------------------------------------------------------------------
__global__ __launch_bounds__(128) void norm_rope(const float* __restrict__ qg,
                                                 const float* __restrict__ kg,
                                                 const float* __restrict__ vg,
                                                 const float* __restrict__ qw,
                                                 const float* __restrict__ kw,
                                                 float* __restrict__ qr,
                                                 float* __restrict__ kc,
                                                 float* __restrict__ vc) {
    const int slot = blockIdx.x;   // 0..39
    const int s    = blockIdx.y;   // 0..2047
    const int d    = threadIdx.x;  // 0..127

    float x;
    const float* w;
    if (slot < NHEADS) {
        x = qg[(size_t)s * QKDIM + slot * HD + d];
        w = qw;
    } else {
        const int g = slot - NHEADS;
        x = kg[(size_t)s * KVDIM + g * HD + d];
        w = kw;
        vc[((size_t)g * S_LEN + s) * HD + d] = vg[(size_t)s * KVDIM + g * HD + d];
    }

    float ssum = x * x;
#pragma unroll
    for (int off = 1; off < 64; off <<= 1) ssum += __shfl_xor(ssum, off);
    __shared__ float red[2];
    __shared__ float ynorm[128];
    if ((d & 63) == 0) red[d >> 6] = ssum;
    __syncthreads();
    const float mean = (red[0] + red[1]) * (1.0f / 128.0f);
    const float y = x * rsqrtf(mean + 1e-6f) * w[d];
    ynorm[d] = y;
    __syncthreads();
    const float partner = ynorm[d ^ 64];

    const int i = d & 63;
    const double invf = pow(5.0e6, -(double)i / 64.0);
    const double ang = (double)s * invf;
    const float cs = (float)cos(ang);
    const float sn = (float)sin(ang);
    const float outv = (d < 64) ? (y * cs - partner * sn)
                                : (y * cs + partner * sn);

    if (slot < NHEADS) {
        qr[((size_t)slot * S_LEN + s) * HD + d] = outv * 0.08838834764831845f;
    } else {
        kc[((size_t)(slot - NHEADS) * S_LEN + s) * HD + d] = outv;
    }
}

// ---------------------------------------------------------------------------
// Flash-style causal attention (unchanged from round 1).
// ---------------------------------------------------------------------------
__global__ __launch_bounds__(256) void attn_fwd(const float* __restrict__ Q,
                                                const float* __restrict__ Kc,
                                                const float* __restrict__ Vc,
                                                float* __restrict__ O) {
    __shared__ float Qs[32][129];
    __shared__ float KVs[64][129];
    __shared__ float Ps[32][65];

    const int h  = blockIdx.y;
    const int g  = h >> 2;
    const int q0 = blockIdx.x * 32;
    const int tid = threadIdx.x;
    const int tx = tid & 31;
    const int ty = tid >> 5;

    const float* Qbase = Q + ((size_t)h * S_LEN + q0) * HD;
    for (int e = tid; e < 32 * 32; e += 256) {
        const int r = e >> 5, c = (e & 31) << 2;
        float4 v = *(const float4*)(Qbase + r * HD + c);
        Qs[r][c] = v.x; Qs[r][c+1] = v.y; Qs[r][c+2] = v.z; Qs[r][c+3] = v.w;
    }

    float m_i[4], l_i[4], o_acc[4][4];
#pragma unroll
    for (int i = 0; i < 4; ++i) {
        m_i[i] = -INFINITY; l_i[i] = 0.0f;
#pragma unroll
        for (int j = 0; j < 4; ++j) o_acc[i][j] = 0.0f;
    }

    const int kt_max = (q0 + 31) >> 6;
    for (int kt = 0; kt <= kt_max; ++kt) {
        __syncthreads();
        const float* Kbase = Kc + ((size_t)g * S_LEN + kt * 64) * HD;
        for (int e = tid; e < 64 * 32; e += 256) {
            const int r = e >> 5, c = (e & 31) << 2;
            float4 v = *(const float4*)(Kbase + r * HD + c);
            KVs[r][c] = v.x; KVs[r][c+1] = v.y; KVs[r][c+2] = v.z; KVs[r][c+3] = v.w;
        }
        __syncthreads();

        float sc[4][2] = {};
#pragma unroll 4
        for (int d = 0; d < HD; ++d) {
            float a[4], b[2];
#pragma unroll
            for (int i = 0; i < 4; ++i) a[i] = Qs[ty*4+i][d];
            b[0] = KVs[tx*2][d]; b[1] = KVs[tx*2+1][d];
#pragma unroll
            for (int i = 0; i < 4; ++i) {
                sc[i][0] = fmaf(a[i], b[0], sc[i][0]);
                sc[i][1] = fmaf(a[i], b[1], sc[i][1]);
            }
        }

#pragma unroll
        for (int i = 0; i < 4; ++i) {
            const int row_g = q0 + ty*4 + i;
#pragma unroll
            for (int j = 0; j < 2; ++j) {
                const int col_g = kt*64 + tx*2 + j;
                if (col_g > row_g) sc[i][j] = -INFINITY;
            }
            float rowmax = fmaxf(sc[i][0], sc[i][1]);
#pragma unroll
            for (int off = 16; off; off >>= 1)
                rowmax = fmaxf(rowmax, __shfl_xor(rowmax, off));
            const float m_new = fmaxf(m_i[i], rowmax);
            const float alpha = expf(m_i[i] - m_new);
            const float p0 = expf(sc[i][0] - m_new);
            const float p1 = expf(sc[i][1] - m_new);
            float psum = p0 + p1;
#pragma unroll
            for (int off = 16; off; off >>= 1)
                psum += __shfl_xor(psum, off);
            l_i[i] = l_i[i] * alpha + psum;
            m_i[i] = m_new;
#pragma unroll
            for (int j = 0; j < 4; ++j) o_acc[i][j] *= alpha;
            Ps[ty*4+i][tx*2]   = p0;
            Ps[ty*4+i][tx*2+1] = p1;
        }
        __syncthreads();

        const float* Vbase = Vc + ((size_t)g * S_LEN + kt * 64) * HD;
        for (int e = tid; e < 64 * 32; e += 256) {
            const int r = e >> 5, c = (e & 31) << 2;
            float4 v = *(const float4*)(Vbase + r * HD + c);
            KVs[r][c] = v.x; KVs[r][c+1] = v.y; KVs[r][c+2] = v.z; KVs[r][c+3] = v.w;
        }
        __syncthreads();

#pragma unroll 2
        for (int kk = 0; kk < 64; ++kk) {
            float p[4], v[4];
#pragma unroll
            for (int i = 0; i < 4; ++i) p[i] = Ps[ty*4+i][kk];
#pragma unroll
            for (int j = 0; j < 4; ++j) v[j] = KVs[kk][tx*4+j];
#pragma unroll
            for (int i = 0; i < 4; ++i)
#pragma unroll
                for (int j = 0; j < 4; ++j)
                    o_acc[i][j] = fmaf(p[i], v[j], o_acc[i][j]);
        }
    }

#pragma unroll
    for (int i = 0; i < 4; ++i) {
        const float inv_l = 1.0f / l_i[i];
        const int s = q0 + ty*4 + i;
#pragma unroll
        for (int j = 0; j < 4; ++j)
            O[(size_t)s * QKDIM + h * HD + tx*4 + j] = o_acc[i][j] * inv_l;
    }
}

// ---------------------------------------------------------------------------
extern "C" void kernel_launch(void* const* d_in, const int* in_sizes, int n_in,
                              void* d_out, int out_size, void* d_ws, size_t ws_size,
                              hipStream_t stream) {
    const float* x  = (const float*)d_in[0];   // [2048][2560]
    const float* Wq = (const float*)d_in[1];   // [4096][2560]
    const float* Wk = (const float*)d_in[2];   // [1024][2560]
    const float* Wv = (const float*)d_in[3];   // [1024][2560]
    const float* Wo = (const float*)d_in[4];   // [2560][4096]
    const float* qw = (const float*)d_in[5];   // [128]
    const float* kw = (const float*)d_in[6];   // [128]

    float* out     = (float*)d_out;                         // [2048][2560]
    float* cache_k = out + (size_t)S_LEN * DMODEL;          // [8][2048][128]
    float* cache_v = cache_k + (size_t)NKV * S_LEN * HD;    // [8][2048][128]

    // fp32 workspace (83.9 MB total, same footprint as round 1)
    float* ws = (float*)d_ws;
    float* qg = ws;                                   // 2048*4096
    float* kg = qg + (size_t)S_LEN * QKDIM;           // 2048*1024
    float* vg = kg + (size_t)S_LEN * KVDIM;           // 2048*1024
    float* qr = vg + (size_t)S_LEN * KVDIM;           // 32*2048*128
    float* ao = qg;                                   // reuse after norm_rope

    // bf16 aliases over dead fp32 regions:
    //  - Wq/Wk/Wv bf16 live in qr's region during steps 1-2 (qr written step 3)
    //  - Wo  bf16 lives in qr's region after attention (qr dead)
    //  - ao  bf16 lives in kg+vg region (dead after norm_rope)
    //  - x   bf16 lives in d_out's out region (overwritten by final GEMM)
    u16* Wqb = (u16*)qr;                              // 10485760 elems
    u16* Wkb = Wqb + (size_t)KVDIM * DMODEL * 4;      // offset 10485760
    u16* Wvb = Wkb + (size_t)KVDIM * DMODEL;          // (fits: 15.7M <= 16.7M u16)
    u16* Wob = (u16*)qr;
    u16* aob = (u16*)kg;                              // 8388608 elems == kg+vg
    u16* xb  = (u16*)out;                             // 5242880 <= 10485760 u16

    // 1) fp32 -> bf16 converts
    f32_to_bf16_k<<<1024, 256, 0, stream>>>(x,  xb,  S_LEN * DMODEL / 4);
    f32_to_bf16_k<<<1024, 256, 0, stream>>>(Wq, Wqb, QKDIM * DMODEL / 4);
    f32_to_bf16_k<<<1024, 256, 0, stream>>>(Wk, Wkb, KVDIM * DMODEL / 4);
    f32_to_bf16_k<<<1024, 256, 0, stream>>>(Wv, Wvb, KVDIM * DMODEL / 4);

    // 2) QKV projections (bf16 MFMA, fp32 out)
    gemm_bf16_nt<<<dim3(QKDIM/128, S_LEN/128), 256, 0, stream>>>(
        (const __bf16*)xb, (const __bf16*)Wqb, qg, S_LEN, QKDIM, DMODEL);
    gemm_bf16_nt<<<dim3(KVDIM/128, S_LEN/128), 256, 0, stream>>>(
        (const __bf16*)xb, (const __bf16*)Wkb, kg, S_LEN, KVDIM, DMODEL);
    gemm_bf16_nt<<<dim3(KVDIM/128, S_LEN/128), 256, 0, stream>>>(
        (const __bf16*)xb, (const __bf16*)Wvb, vg, S_LEN, KVDIM, DMODEL);

    // 3) RMSNorm + RoPE (+ V transpose into cache)
    norm_rope<<<dim3(NHEADS + NKV, S_LEN), 128, 0, stream>>>(qg, kg, vg, qw, kw,
                                                             qr, cache_k, cache_v);

    // 4) causal GQA attention (fp32, unchanged)
    attn_fwd<<<dim3(S_LEN/32, NHEADS), 256, 0, stream>>>(qr, cache_k, cache_v, ao);

    // 5) convert attention output + Wo to bf16
    f32_to_bf16_k<<<1024, 256, 0, stream>>>(ao, aob, S_LEN * QKDIM / 4);
    f32_to_bf16_k<<<1024, 256, 0, stream>>>(Wo, Wob, DMODEL * QKDIM / 4);

    // 6) output projection
    gemm_bf16_nt<<<dim3(DMODEL/128, S_LEN/128), 256, 0, stream>>>(
        (const __bf16*)aob, (const __bf16*)Wob, out, S_LEN, DMODEL, QKDIM);
}

// Round 3
// 862.031 us; speedup vs baseline: 4.8817x; 2.7805x over previous
//
#include <hip/hip_runtime.h>
#include <hip/hip_bf16.h>
#include <math.h>

#define S_LEN  2048
#define DMODEL 2560
#define NHEADS 32
#define NKV    8
#define HD     128
#define QKDIM  (NHEADS * HD)   // 4096
#define KVDIM  (NKV * HD)      // 1024

typedef __bf16 bf16x8 __attribute__((ext_vector_type(8)));
typedef float  f32x4  __attribute__((ext_vector_type(4)));
typedef unsigned short u16;

#define AS1 __attribute__((address_space(1)))
#define AS3 __attribute__((address_space(3)))

__device__ __forceinline__ void load16_to_lds(const void* g, void* l) {
    __builtin_amdgcn_global_load_lds((const AS1 void*)g, (AS3 void*)l, 16, 0, 0);
}

__device__ __forceinline__ u16 f2bf(float f) {
    unsigned u = __builtin_bit_cast(unsigned, f);
    return (u16)((u + 0x7fff + ((u >> 16) & 1)) >> 16);   // RTNE
}

// ---------------------------------------------------------------------------
// fp32 -> bf16 convert, 4 elements/thread, grid-stride. n4 = n/4.
// ---------------------------------------------------------------------------
__global__ __launch_bounds__(256) void f32_to_bf16_k(const float* __restrict__ in,
                                                     u16* __restrict__ out, int n4) {
    int i = blockIdx.x * 256 + threadIdx.x;
    const int stride = gridDim.x * 256;
    for (; i < n4; i += stride) {
        float4 v = ((const float4*)in)[i];
        ushort4 r;
        r.x = f2bf(v.x); r.y = f2bf(v.y); r.z = f2bf(v.z); r.w = f2bf(v.w);
        ((ushort4*)out)[i] = r;
    }
}

// ---------------------------------------------------------------------------
// bf16 MFMA NT GEMM (m97 pattern, unchanged from round 2 — passed).
// ---------------------------------------------------------------------------
__global__ __launch_bounds__(256) void gemm_bf16_nt(const __bf16* __restrict__ A,
                                                    const __bf16* __restrict__ B,
                                                    float* __restrict__ C,
                                                    int M, int N, int K) {
    __shared__ __align__(16) __bf16 Als[128 * 32];
    __shared__ __align__(16) __bf16 Bls[128 * 32];
    const int tid  = threadIdx.x;
    const int lane = tid & 63;
    const int wave = tid >> 6;
    const int wm   = wave >> 1, wn = wave & 1;
    const int m0   = blockIdx.y * 128;
    const int n0   = blockIdx.x * 128;
    const int frow = lane & 15;
    const int fkq  = lane >> 4;

    f32x4 acc[4][4];
#pragma unroll
    for (int t = 0; t < 4; ++t)
#pragma unroll
        for (int u = 0; u < 4; ++u)
            acc[t][u] = (f32x4){0.f, 0.f, 0.f, 0.f};

    for (int k0 = 0; k0 < K; k0 += 32) {
        __syncthreads();
#pragma unroll
        for (int i = 0; i < 2; ++i) {
            const int mt  = i * 4 + wave;
            const int row = mt * 16 + frow;
            const int col = k0 + fkq * 8;
            __bf16* ldsA = &Als[(size_t)(i * 256 + wave * 64) * 8];
            __bf16* ldsB = &Bls[(size_t)(i * 256 + wave * 64) * 8];
            load16_to_lds(A + (size_t)(m0 + row) * K + col, ldsA);
            load16_to_lds(B + (size_t)(n0 + row) * K + col, ldsB);
        }
        __syncthreads();

        bf16x8 af[4], bfr[4];
#pragma unroll
        for (int t = 0; t < 4; ++t)
            af[t]  = *(const bf16x8*)&Als[((wm * 4 + t) * 64 + lane) * 8];
#pragma unroll
        for (int u = 0; u < 4; ++u)
            bfr[u] = *(const bf16x8*)&Bls[((wn * 4 + u) * 64 + lane) * 8];
#pragma unroll
        for (int t = 0; t < 4; ++t)
#pragma unroll
            for (int u = 0; u < 4; ++u)
                acc[t][u] = __builtin_amdgcn_mfma_f32_16x16x32_bf16(
                                af[t], bfr[u], acc[t][u], 0, 0, 0);
    }

    const int crow = (lane >> 4) * 4;
    const int ccol = lane & 15;
#pragma unroll
    for (int t = 0; t < 4; ++t) {
        const int gr = m0 + (wm * 4 + t) * 16 + crow;
#pragma unroll
        for (int u = 0; u < 4; ++u) {
            const int gc = n0 + (wn * 4 + u) * 16 + ccol;
#pragma unroll
            for (int r = 0; r < 4; ++r)
                C[(size_t)(gr + r) * N + gc] = acc[t][u][r];
        }
    }
}

// ---------------------------------------------------------------------------
// Per-(s, head) RMSNorm + RoPE.  Q out: bf16 [h][s][d], scaled by
// (1/sqrt(HD))*log2(e)  (log2e folded so attention softmax can use exp2).
// K out: fp32 cache (d_out) AND bf16 copy [g][s][d] for attention.
// V: fp32 cache copy (d_out).
// ---------------------------------------------------------------------------
__global__ __launch_bounds__(128) void norm_rope(const float* __restrict__ qg,
                                                 const float* __restrict__ kg,
                                                 const float* __restrict__ vg,
                                                 const float* __restrict__ qw,
                                                 const float* __restrict__ kw,
                                                 u16* __restrict__ qrb,
                                                 float* __restrict__ kc,
                                                 u16* __restrict__ kcb,
                                                 float* __restrict__ vc) {
    const int slot = blockIdx.x;   // 0..39
    const int s    = blockIdx.y;   // 0..2047
    const int d    = threadIdx.x;  // 0..127

    float x;
    const float* w;
    if (slot < NHEADS) {
        x = qg[(size_t)s * QKDIM + slot * HD + d];
        w = qw;
    } else {
        const int g = slot - NHEADS;
        x = kg[(size_t)s * KVDIM + g * HD + d];
        w = kw;
        vc[((size_t)g * S_LEN + s) * HD + d] = vg[(size_t)s * KVDIM + g * HD + d];
    }

    float ssum = x * x;
#pragma unroll
    for (int off = 1; off < 64; off <<= 1) ssum += __shfl_xor(ssum, off);
    __shared__ float red[2];
    __shared__ float ynorm[128];
    if ((d & 63) == 0) red[d >> 6] = ssum;
    __syncthreads();
    const float mean = (red[0] + red[1]) * (1.0f / 128.0f);
    const float y = x * rsqrtf(mean + 1e-6f) * w[d];
    ynorm[d] = y;
    __syncthreads();
    const float partner = ynorm[d ^ 64];

    const int i = d & 63;
    const double invf = pow(5.0e6, -(double)i / 64.0);
    const double ang = (double)s * invf;
    const float cs = (float)cos(ang);
    const float sn = (float)sin(ang);
    const float outv = (d < 64) ? (y * cs - partner * sn)
                                : (y * cs + partner * sn);

    if (slot < NHEADS) {
        // scale = 1/sqrt(128) * log2(e)
        qrb[((size_t)slot * S_LEN + s) * HD + d] = f2bf(outv * 0.12751743f);
    } else {
        const int g = slot - NHEADS;
        kc [((size_t)g * S_LEN + s) * HD + d] = outv;
        kcb[((size_t)g * S_LEN + s) * HD + d] = f2bf(outv);
    }
}

// ---------------------------------------------------------------------------
// V transpose: vg fp32 [s][g*128+d]  ->  vtb bf16 [g][d][s]
// grid (8, 32, 2): 64s x 64d tile per block.
// ---------------------------------------------------------------------------
__global__ __launch_bounds__(256) void v_transpose(const float* __restrict__ vg,
                                                   u16* __restrict__ vtb) {
    __shared__ float Ts[64][65];
    const int g  = blockIdx.x;
    const int s0 = blockIdx.y * 64;
    const int d0 = blockIdx.z * 64;
    const int tid = threadIdx.x;

    for (int e = tid; e < 64 * 16; e += 256) {
        const int r = e >> 4, c = (e & 15) << 2;
        float4 v = *(const float4*)(vg + (size_t)(s0 + r) * KVDIM + g * HD + d0 + c);
        Ts[r][c] = v.x; Ts[r][c+1] = v.y; Ts[r][c+2] = v.z; Ts[r][c+3] = v.w;
    }
    __syncthreads();
    for (int e = tid; e < 64 * 16; e += 256) {
        const int d = e >> 4, c = (e & 15) << 2;
        ushort4 o;
        o.x = f2bf(Ts[c+0][d]); o.y = f2bf(Ts[c+1][d]);
        o.z = f2bf(Ts[c+2][d]); o.w = f2bf(Ts[c+3][d]);
        *(ushort4*)(vtb + ((size_t)g * HD + d0 + d) * S_LEN + s0 + c) = o;
    }
}

// ---------------------------------------------------------------------------
// MFMA flash attention.  Block = 4 waves; 64-query tile per (head, q-tile);
// 64-key tiles with online softmax.  Wave w owns query rows [w*16, w*16+16).
// Q/K/V staged to LDS in fragment-chunk order via global_load_lds(16B).
// P (bf16) round-trips through LDS into A-operand layout for the PV MFMA.
// V comes pre-transposed [g][d][s] so its B-fragments are contiguous.
// Output written directly as bf16 [s][h*128+d] for the Wo GEMM.
// LDS: 16+16+16+8 = 56 KB.
// ---------------------------------------------------------------------------
__global__ __launch_bounds__(256) void attn_mfma(const __bf16* __restrict__ Qb,
                                                 const __bf16* __restrict__ Kb,
                                                 const __bf16* __restrict__ Vt,
                                                 u16* __restrict__ Ob) {
    __shared__ __align__(16) __bf16 Qls[4 * 4 * 64 * 8];  // [mtile][kstep][lane][8]
    __shared__ __align__(16) __bf16 Kls[4 * 4 * 64 * 8];  // [ntile][kstep][lane][8]
    __shared__ __align__(16) __bf16 Vls[8 * 2 * 64 * 8];  // [dtile][kstep][lane][8]
    __shared__ __align__(16) __bf16 Pls[4 * 2 * 64 * 8];  // [wave ][kstep][lane][8]

    const int h    = blockIdx.y;
    const int g    = h >> 2;
    const int q0   = blockIdx.x * 64;
    const int tid  = threadIdx.x;
    const int lane = tid & 63;
    const int wave = tid >> 6;
    const int fr   = lane & 15;   // fragment row / col
    const int fq   = lane >> 4;   // k-quad

    // stage Q tile (once): wave w stages mtile=w
    {
        const __bf16* Qg = Qb + ((size_t)h * S_LEN + q0 + wave * 16 + fr) * HD;
#pragma unroll
        for (int ks = 0; ks < 4; ++ks)
            load16_to_lds(Qg + ks * 32 + fq * 8, &Qls[(size_t)((wave * 4 + ks) * 64) * 8]);
    }

    float m_i[4], l_i[4];
    f32x4 o_acc[8];
#pragma unroll
    for (int r = 0; r < 4; ++r) { m_i[r] = -INFINITY; l_i[r] = 0.0f; }
#pragma unroll
    for (int dt = 0; dt < 8; ++dt) o_acc[dt] = (f32x4){0.f, 0.f, 0.f, 0.f};

    const int kt_max = blockIdx.x;
    for (int kt = 0; kt <= kt_max; ++kt) {
        __syncthreads();   // prev iter's K/V LDS reads done
        // stage K tile: wave w stages ntile=w
        {
            const __bf16* Kg = Kb + ((size_t)g * S_LEN + kt * 64 + wave * 16 + fr) * HD;
#pragma unroll
            for (int ks = 0; ks < 4; ++ks)
                load16_to_lds(Kg + ks * 32 + fq * 8, &Kls[(size_t)((wave * 4 + ks) * 64) * 8]);
        }
        // stage V^T tile: wave w stages dtiles {2w, 2w+1}
#pragma unroll
        for (int i = 0; i < 2; ++i) {
            const int dt = wave * 2 + i;
            const __bf16* Vg = Vt + ((size_t)g * HD + dt * 16 + fr) * S_LEN + kt * 64;
#pragma unroll
            for (int ks = 0; ks < 2; ++ks)
                load16_to_lds(Vg + ks * 32 + fq * 8, &Vls[(size_t)((dt * 2 + ks) * 64) * 8]);
        }
        __syncthreads();   // staging complete (vmcnt drained by barrier)

        // ---- QK^T: wave's 16 rows x 64 cols ----
        f32x4 s_acc[4];
#pragma unroll
        for (int u = 0; u < 4; ++u) s_acc[u] = (f32x4){0.f, 0.f, 0.f, 0.f};
        bf16x8 aq[4];
#pragma unroll
        for (int ks = 0; ks < 4; ++ks)
            aq[ks] = *(const bf16x8*)&Qls[((wave * 4 + ks) * 64 + lane) * 8];
#pragma unroll
        for (int u = 0; u < 4; ++u)
#pragma unroll
            for (int ks = 0; ks < 4; ++ks)
                s_acc[u] = __builtin_amdgcn_mfma_f32_16x16x32_bf16(
                               aq[ks],
                               *(const bf16x8*)&Kls[((u * 4 + ks) * 64 + lane) * 8],
                               s_acc[u], 0, 0, 0);

        // ---- causal mask (diagonal tile only; logits are base-2 scaled) ----
        if (kt == kt_max) {
#pragma unroll
            for (int u = 0; u < 4; ++u)
#pragma unroll
                for (int r = 0; r < 4; ++r)
                    if (kt * 64 + u * 16 + fr > q0 + wave * 16 + fq * 4 + r)
                        s_acc[u][r] = -INFINITY;
        }

        // ---- online softmax (per row = fq*4+r; reduce over quad's 16 lanes) ----
#pragma unroll
        for (int r = 0; r < 4; ++r) {
            float mx = fmaxf(fmaxf(s_acc[0][r], s_acc[1][r]),
                             fmaxf(s_acc[2][r], s_acc[3][r]));
#pragma unroll
            for (int off = 1; off < 16; off <<= 1)
                mx = fmaxf(mx, __shfl_xor(mx, off));
            const float m_new = fmaxf(m_i[r], mx);
            const float alpha = exp2f(m_i[r] - m_new);
            m_i[r] = m_new;

            float p[4], psum = 0.0f;
#pragma unroll
            for (int u = 0; u < 4; ++u) {
                p[u] = exp2f(s_acc[u][r] - m_new);
                psum += p[u];
            }
#pragma unroll
            for (int off = 1; off < 16; off <<= 1)
                psum += __shfl_xor(psum, off);
            l_i[r] = l_i[r] * alpha + psum;

#pragma unroll
            for (int dt = 0; dt < 8; ++dt) o_acc[dt][r] *= alpha;

            // write P into A-operand layout (wave-private LDS region)
#pragma unroll
            for (int u = 0; u < 4; ++u) {
                const int k = u * 16 + fr;
                const int m = fq * 4 + r;
                const int idx = ((wave * 2 + (k >> 5)) * 64 + ((k >> 3) & 3) * 16 + m) * 8
                                + (k & 7);
                ((u16*)Pls)[idx] = f2bf(p[u]);
            }
        }

        // ---- PV: same-wave LDS write->read is ordered; no barrier needed ----
        bf16x8 ap[2];
#pragma unroll
        for (int ks = 0; ks < 2; ++ks)
            ap[ks] = *(const bf16x8*)&Pls[((wave * 2 + ks) * 64 + lane) * 8];
#pragma unroll
        for (int dt = 0; dt < 8; ++dt)
#pragma unroll
            for (int ks = 0; ks < 2; ++ks)
                o_acc[dt] = __builtin_amdgcn_mfma_f32_16x16x32_bf16(
                                ap[ks],
                                *(const bf16x8*)&Vls[((dt * 2 + ks) * 64 + lane) * 8],
                                o_acc[dt], 0, 0, 0);
    }

    // ---- epilogue: normalize, write bf16 [s][h*128+d] ----
#pragma unroll
    for (int r = 0; r < 4; ++r) {
        const float inv_l = 1.0f / l_i[r];
        const int s = q0 + wave * 16 + fq * 4 + r;
#pragma unroll
        for (int dt = 0; dt < 8; ++dt)
            Ob[(size_t)s * QKDIM + h * HD + dt * 16 + fr] = f2bf(o_acc[dt][r] * inv_l);
    }
}

// ---------------------------------------------------------------------------
extern "C" void kernel_launch(void* const* d_in, const int* in_sizes, int n_in,
                              void* d_out, int out_size, void* d_ws, size_t ws_size,
                              hipStream_t stream) {
    const float* x  = (const float*)d_in[0];
    const float* Wq = (const float*)d_in[1];
    const float* Wk = (const float*)d_in[2];
    const float* Wv = (const float*)d_in[3];
    const float* Wo = (const float*)d_in[4];
    const float* qw = (const float*)d_in[5];
    const float* kw = (const float*)d_in[6];

    float* out     = (float*)d_out;
    float* cache_k = out + (size_t)S_LEN * DMODEL;
    float* cache_v = cache_k + (size_t)NKV * S_LEN * HD;

    float* ws = (float*)d_ws;
    float* qg = ws;                                   // 8M floats
    float* kg = qg + (size_t)S_LEN * QKDIM;           // 2M floats
    float* vg = kg + (size_t)S_LEN * KVDIM;           // 2M floats
    float* rg = vg + (size_t)S_LEN * KVDIM;           // region R: 8M floats (32 MB)

    // region R phase A (converts + QKV GEMMs): weight bf16 copies
    u16* Wqb = (u16*)rg;                              // 10.49M u16
    u16* Wkb = Wqb + (size_t)QKDIM * DMODEL;          // 2.62M
    u16* Wvb = Wkb + (size_t)KVDIM * DMODEL;          // 2.62M  (15.73M <= 16M ok)
    // region R phase B (norm/attention): bf16 Q, K, V^T
    u16* qrb = (u16*)rg;                              // 8.39M u16
    u16* kcb = qrb + (size_t)NHEADS * S_LEN * HD;     // 2.10M
    u16* vtb = kcb + (size_t)NKV * S_LEN * HD;        // 2.10M  (12.6M <= 16M ok)
    // region R phase C (output GEMM): Wo bf16
    u16* Wob = (u16*)rg;                              // 10.49M u16
    // attention output bf16 exactly fills kg+vg (dead after v_transpose)
    u16* aob = (u16*)kg;                              // 8.39M u16 == 4M floats
    // x bf16 lives in d_out's out region (overwritten only by final GEMM)
    u16* xb  = (u16*)out;

    // 1) converts
    f32_to_bf16_k<<<1024, 256, 0, stream>>>(x,  xb,  S_LEN * DMODEL / 4);
    f32_to_bf16_k<<<1024, 256, 0, stream>>>(Wq, Wqb, QKDIM * DMODEL / 4);
    f32_to_bf16_k<<<1024, 256, 0, stream>>>(Wk, Wkb, KVDIM * DMODEL / 4);
    f32_to_bf16_k<<<1024, 256, 0, stream>>>(Wv, Wvb, KVDIM * DMODEL / 4);

    // 2) QKV projections
    gemm_bf16_nt<<<dim3(QKDIM/128, S_LEN/128), 256, 0, stream>>>(
        (const __bf16*)xb, (const __bf16*)Wqb, qg, S_LEN, QKDIM, DMODEL);
    gemm_bf16_nt<<<dim3(KVDIM/128, S_LEN/128), 256, 0, stream>>>(
        (const __bf16*)xb, (const __bf16*)Wkb, kg, S_LEN, KVDIM, DMODEL);
    gemm_bf16_nt<<<dim3(KVDIM/128, S_LEN/128), 256, 0, stream>>>(
        (const __bf16*)xb, (const __bf16*)Wvb, vg, S_LEN, KVDIM, DMODEL);

    // 3) RMSNorm + RoPE (+ fp32 caches into d_out, bf16 Q/K for attention)
    norm_rope<<<dim3(NHEADS + NKV, S_LEN), 128, 0, stream>>>(
        qg, kg, vg, qw, kw, qrb, cache_k, kcb, cache_v);

    // 4) V^T bf16 for attention
    v_transpose<<<dim3(NKV, S_LEN/64, HD/64), 256, 0, stream>>>(vg, vtb);

    // 5) MFMA flash attention -> bf16 output
    attn_mfma<<<dim3(S_LEN/64, NHEADS), 256, 0, stream>>>(
        (const __bf16*)qrb, (const __bf16*)kcb, (const __bf16*)vtb, aob);

    // 6) Wo convert + output projection
    f32_to_bf16_k<<<1024, 256, 0, stream>>>(Wo, Wob, DMODEL * QKDIM / 4);
    gemm_bf16_nt<<<dim3(DMODEL/128, S_LEN/128), 256, 0, stream>>>(
        (const __bf16*)aob, (const __bf16*)Wob, out, S_LEN, DMODEL, QKDIM);
}

// Round 4
// 631.735 us; speedup vs baseline: 6.6613x; 1.3645x over previous
//
#include <hip/hip_runtime.h>
#include <hip/hip_bf16.h>
#include <math.h>

#define S_LEN  2048
#define DMODEL 2560
#define NHEADS 32
#define NKV    8
#define HD     128
#define QKDIM  (NHEADS * HD)   // 4096
#define KVDIM  (NKV * HD)      // 1024
#define KVCAT  (2 * KVDIM)     // 2048 (K and V concatenated per row)

typedef __bf16 bf16x8 __attribute__((ext_vector_type(8)));
typedef float  f32x4  __attribute__((ext_vector_type(4)));
typedef unsigned short u16;

#define AS1 __attribute__((address_space(1)))
#define AS3 __attribute__((address_space(3)))

__device__ __forceinline__ void load16_to_lds(const void* g, void* l) {
    __builtin_amdgcn_global_load_lds((const AS1 void*)g, (AS3 void*)l, 16, 0, 0);
}

__device__ __forceinline__ u16 f2bf(float f) {
    unsigned u = __builtin_bit_cast(unsigned, f);
    return (u16)((u + 0x7fff + ((u >> 16) & 1)) >> 16);   // RTNE
}

// ---------------------------------------------------------------------------
// fp32 -> bf16 convert, 4 elements/thread, grid-stride. n4 = n/4.
// ---------------------------------------------------------------------------
__global__ __launch_bounds__(256) void f32_to_bf16_k(const float* __restrict__ in,
                                                     u16* __restrict__ out, int n4) {
    int i = blockIdx.x * 256 + threadIdx.x;
    const int stride = gridDim.x * 256;
    for (; i < n4; i += stride) {
        float4 v = ((const float4*)in)[i];
        ushort4 r;
        r.x = f2bf(v.x); r.y = f2bf(v.y); r.z = f2bf(v.z); r.w = f2bf(v.w);
        ((ushort4*)out)[i] = r;
    }
}

// ---------------------------------------------------------------------------
// RoPE table: ct/st[s][i] fp32, computed in double (131K threads, trivial).
// ---------------------------------------------------------------------------
__global__ __launch_bounds__(64) void rope_table(float* __restrict__ ct,
                                                 float* __restrict__ st) {
    const int s = blockIdx.x;
    const int i = threadIdx.x;           // 0..63
    const double invf = pow(5.0e6, -(double)i / 64.0);
    const double ang  = (double)s * invf;
    ct[s * 64 + i] = (float)cos(ang);
    st[s * 64 + i] = (float)sin(ang);
}

// ---------------------------------------------------------------------------
// bf16 MFMA NT GEMM (m97 pattern, unchanged — passed rounds 2-3).
// ---------------------------------------------------------------------------
__global__ __launch_bounds__(256) void gemm_bf16_nt(const __bf16* __restrict__ A,
                                                    const __bf16* __restrict__ B,
                                                    float* __restrict__ C,
                                                    int M, int N, int K) {
    __shared__ __align__(16) __bf16 Als[128 * 32];
    __shared__ __align__(16) __bf16 Bls[128 * 32];
    const int tid  = threadIdx.x;
    const int lane = tid & 63;
    const int wave = tid >> 6;
    const int wm   = wave >> 1, wn = wave & 1;
    const int m0   = blockIdx.y * 128;
    const int n0   = blockIdx.x * 128;
    const int frow = lane & 15;
    const int fkq  = lane >> 4;

    f32x4 acc[4][4];
#pragma unroll
    for (int t = 0; t < 4; ++t)
#pragma unroll
        for (int u = 0; u < 4; ++u)
            acc[t][u] = (f32x4){0.f, 0.f, 0.f, 0.f};

    for (int k0 = 0; k0 < K; k0 += 32) {
        __syncthreads();
#pragma unroll
        for (int i = 0; i < 2; ++i) {
            const int mt  = i * 4 + wave;
            const int row = mt * 16 + frow;
            const int col = k0 + fkq * 8;
            __bf16* ldsA = &Als[(size_t)(i * 256 + wave * 64) * 8];
            __bf16* ldsB = &Bls[(size_t)(i * 256 + wave * 64) * 8];
            load16_to_lds(A + (size_t)(m0 + row) * K + col, ldsA);
            load16_to_lds(B + (size_t)(n0 + row) * K + col, ldsB);
        }
        __syncthreads();

        bf16x8 af[4], bfr[4];
#pragma unroll
        for (int t = 0; t < 4; ++t)
            af[t]  = *(const bf16x8*)&Als[((wm * 4 + t) * 64 + lane) * 8];
#pragma unroll
        for (int u = 0; u < 4; ++u)
            bfr[u] = *(const bf16x8*)&Bls[((wn * 4 + u) * 64 + lane) * 8];
#pragma unroll
        for (int t = 0; t < 4; ++t)
#pragma unroll
            for (int u = 0; u < 4; ++u)
                acc[t][u] = __builtin_amdgcn_mfma_f32_16x16x32_bf16(
                                af[t], bfr[u], acc[t][u], 0, 0, 0);
    }

    const int crow = (lane >> 4) * 4;
    const int ccol = lane & 15;
#pragma unroll
    for (int t = 0; t < 4; ++t) {
        const int gr = m0 + (wm * 4 + t) * 16 + crow;
#pragma unroll
        for (int u = 0; u < 4; ++u) {
            const int gc = n0 + (wn * 4 + u) * 16 + ccol;
#pragma unroll
            for (int r = 0; r < 4; ++r)
                C[(size_t)(gr + r) * N + gc] = acc[t][u][r];
        }
    }
}

// ---------------------------------------------------------------------------
// Fused QKV GEMM: grid (48,16). Wave-uniform base select: n-tiles [0,32)
// hit Wq -> Cq[2048][4096]; n-tiles [32,48) hit Wk||Wv -> Ckv[2048][2048].
// Same body as gemm_bf16_nt otherwise. K = DMODEL.
// ---------------------------------------------------------------------------
__global__ __launch_bounds__(256) void gemm_qkv(const __bf16* __restrict__ A,
                                                const __bf16* __restrict__ Bq,
                                                const __bf16* __restrict__ Bkv,
                                                float* __restrict__ Cq,
                                                float* __restrict__ Ckv) {
    __shared__ __align__(16) __bf16 Als[128 * 32];
    __shared__ __align__(16) __bf16 Bls[128 * 32];
    const int K = DMODEL;
    const int n0g = blockIdx.x * 128;
    const __bf16* B;
    float* C;
    int ldc, n0;
    if (n0g < QKDIM) { B = Bq;  C = Cq;  ldc = QKDIM; n0 = n0g; }
    else             { B = Bkv; C = Ckv; ldc = KVCAT; n0 = n0g - QKDIM; }

    const int tid  = threadIdx.x;
    const int lane = tid & 63;
    const int wave = tid >> 6;
    const int wm   = wave >> 1, wn = wave & 1;
    const int m0   = blockIdx.y * 128;
    const int frow = lane & 15;
    const int fkq  = lane >> 4;

    f32x4 acc[4][4];
#pragma unroll
    for (int t = 0; t < 4; ++t)
#pragma unroll
        for (int u = 0; u < 4; ++u)
            acc[t][u] = (f32x4){0.f, 0.f, 0.f, 0.f};

    for (int k0 = 0; k0 < K; k0 += 32) {
        __syncthreads();
#pragma unroll
        for (int i = 0; i < 2; ++i) {
            const int row = (i * 4 + wave) * 16 + frow;
            const int col = k0 + fkq * 8;
            __bf16* ldsA = &Als[(size_t)(i * 256 + wave * 64) * 8];
            __bf16* ldsB = &Bls[(size_t)(i * 256 + wave * 64) * 8];
            load16_to_lds(A + (size_t)(m0 + row) * K + col, ldsA);
            load16_to_lds(B + (size_t)(n0 + row) * K + col, ldsB);
        }
        __syncthreads();

        bf16x8 af[4], bfr[4];
#pragma unroll
        for (int t = 0; t < 4; ++t)
            af[t]  = *(const bf16x8*)&Als[((wm * 4 + t) * 64 + lane) * 8];
#pragma unroll
        for (int u = 0; u < 4; ++u)
            bfr[u] = *(const bf16x8*)&Bls[((wn * 4 + u) * 64 + lane) * 8];
#pragma unroll
        for (int t = 0; t < 4; ++t)
#pragma unroll
            for (int u = 0; u < 4; ++u)
                acc[t][u] = __builtin_amdgcn_mfma_f32_16x16x32_bf16(
                                af[t], bfr[u], acc[t][u], 0, 0, 0);
    }

    const int crow = (lane >> 4) * 4;
    const int ccol = lane & 15;
#pragma unroll
    for (int t = 0; t < 4; ++t) {
        const int gr = m0 + (wm * 4 + t) * 16 + crow;
#pragma unroll
        for (int u = 0; u < 4; ++u) {
            const int gc = n0 + (wn * 4 + u) * 16 + ccol;
#pragma unroll
            for (int r = 0; r < 4; ++r)
                C[(size_t)(gr + r) * ldc + gc] = acc[t][u][r];
        }
    }
}

// ---------------------------------------------------------------------------
// Per-(s, head) RMSNorm + RoPE, table-driven (no transcendentals).
// Q out: bf16 [h][s][d] scaled by (1/sqrt(HD))*log2(e).
// K out: fp32 cache AND bf16 [g][s][d].  V: fp32 cache copy.
// ---------------------------------------------------------------------------
__global__ __launch_bounds__(128) void norm_rope(const float* __restrict__ qg,
                                                 const float* __restrict__ kv,
                                                 const float* __restrict__ ct,
                                                 const float* __restrict__ st,
                                                 const float* __restrict__ qw,
                                                 const float* __restrict__ kw,
                                                 u16* __restrict__ qrb,
                                                 float* __restrict__ kc,
                                                 u16* __restrict__ kcb,
                                                 float* __restrict__ vc) {
    const int slot = blockIdx.x;   // 0..39
    const int s    = blockIdx.y;   // 0..2047
    const int d    = threadIdx.x;  // 0..127

    float x;
    const float* w;
    if (slot < NHEADS) {
        x = qg[(size_t)s * QKDIM + slot * HD + d];
        w = qw;
    } else {
        const int g = slot - NHEADS;
        x = kv[(size_t)s * KVCAT + g * HD + d];
        w = kw;
        vc[((size_t)g * S_LEN + s) * HD + d] =
            kv[(size_t)s * KVCAT + KVDIM + g * HD + d];
    }

    float ssum = x * x;
#pragma unroll
    for (int off = 1; off < 64; off <<= 1) ssum += __shfl_xor(ssum, off);
    __shared__ float red[2];
    __shared__ float ynorm[128];
    if ((d & 63) == 0) red[d >> 6] = ssum;
    __syncthreads();
    const float mean = (red[0] + red[1]) * (1.0f / 128.0f);
    const float y = x * rsqrtf(mean + 1e-6f) * w[d];
    ynorm[d] = y;
    __syncthreads();
    const float partner = ynorm[d ^ 64];

    const int i = d & 63;
    const float cs = ct[s * 64 + i];
    const float sn = st[s * 64 + i];
    const float outv = (d < 64) ? (y * cs - partner * sn)
                                : (y * cs + partner * sn);

    if (slot < NHEADS) {
        qrb[((size_t)slot * S_LEN + s) * HD + d] = f2bf(outv * 0.12751743f);
    } else {
        const int g = slot - NHEADS;
        kc [((size_t)g * S_LEN + s) * HD + d] = outv;
        kcb[((size_t)g * S_LEN + s) * HD + d] = f2bf(outv);
    }
}

// ---------------------------------------------------------------------------
// V transpose: kv fp32 [s][1024 + g*128+d]  ->  vtb bf16 [g][d][s]
// grid (8, 32, 2): 64s x 64d tile per block.
// ---------------------------------------------------------------------------
__global__ __launch_bounds__(256) void v_transpose(const float* __restrict__ kv,
                                                   u16* __restrict__ vtb) {
    __shared__ float Ts[64][65];
    const int g  = blockIdx.x;
    const int s0 = blockIdx.y * 64;
    const int d0 = blockIdx.z * 64;
    const int tid = threadIdx.x;

    for (int e = tid; e < 64 * 16; e += 256) {
        const int r = e >> 4, c = (e & 15) << 2;
        float4 v = *(const float4*)(kv + (size_t)(s0 + r) * KVCAT + KVDIM
                                       + g * HD + d0 + c);
        Ts[r][c] = v.x; Ts[r][c+1] = v.y; Ts[r][c+2] = v.z; Ts[r][c+3] = v.w;
    }
    __syncthreads();
    for (int e = tid; e < 64 * 16; e += 256) {
        const int d = e >> 4, c = (e & 15) << 2;
        ushort4 o;
        o.x = f2bf(Ts[c+0][d]); o.y = f2bf(Ts[c+1][d]);
        o.z = f2bf(Ts[c+2][d]); o.w = f2bf(Ts[c+3][d]);
        *(ushort4*)(vtb + ((size_t)g * HD + d0 + d) * S_LEN + s0 + c) = o;
    }
}

// ---------------------------------------------------------------------------
// MFMA flash attention v2.  Q fragments hoisted to registers once; Q's LDS
// buffer is then reused for V (QVls).  LDS = 16 (K) + 16 (Q/V) + 8 (P) = 40KB
// -> 4 blocks/CU.  __launch_bounds__(256,4) caps VGPRs at 128.
// ---------------------------------------------------------------------------
__global__ __launch_bounds__(256, 4) void attn_mfma(const __bf16* __restrict__ Qb,
                                                    const __bf16* __restrict__ Kb,
                                                    const __bf16* __restrict__ Vt,
                                                    u16* __restrict__ Ob) {
    __shared__ __align__(16) __bf16 Kls [4 * 4 * 64 * 8];  // 16KB
    __shared__ __align__(16) __bf16 QVls[8 * 2 * 64 * 8];  // 16KB (Q, then V)
    __shared__ __align__(16) __bf16 Pls [4 * 2 * 64 * 8];  // 8KB

    const int h    = blockIdx.y;
    const int g    = h >> 2;
    const int q0   = blockIdx.x * 64;
    const int tid  = threadIdx.x;
    const int lane = tid & 63;
    const int wave = tid >> 6;
    const int fr   = lane & 15;
    const int fq   = lane >> 4;

    // stage Q tile (wave w -> mtile w) into QVls, then hoist into registers
    {
        const __bf16* Qg = Qb + ((size_t)h * S_LEN + q0 + wave * 16 + fr) * HD;
#pragma unroll
        for (int ks = 0; ks < 4; ++ks)
            load16_to_lds(Qg + ks * 32 + fq * 8, &QVls[(size_t)((wave * 4 + ks) * 64) * 8]);
    }
    __syncthreads();   // drains vmcnt: Q visible in LDS
    bf16x8 aq[4];
#pragma unroll
    for (int ks = 0; ks < 4; ++ks)
        aq[ks] = *(const bf16x8*)&QVls[((wave * 4 + ks) * 64 + lane) * 8];
    // pending ds_reads drain at the loop's first __syncthreads before overwrite

    float m_i[4], l_i[4];
    f32x4 o_acc[8];
#pragma unroll
    for (int r = 0; r < 4; ++r) { m_i[r] = -INFINITY; l_i[r] = 0.0f; }
#pragma unroll
    for (int dt = 0; dt < 8; ++dt) o_acc[dt] = (f32x4){0.f, 0.f, 0.f, 0.f};

    const int kt_max = blockIdx.x;
    for (int kt = 0; kt <= kt_max; ++kt) {
        __syncthreads();   // prev iter's LDS reads (and Q hoist) done
        // stage K tile: wave w -> ntile w
        {
            const __bf16* Kg = Kb + ((size_t)g * S_LEN + kt * 64 + wave * 16 + fr) * HD;
#pragma unroll
            for (int ks = 0; ks < 4; ++ks)
                load16_to_lds(Kg + ks * 32 + fq * 8, &Kls[(size_t)((wave * 4 + ks) * 64) * 8]);
        }
        // stage V^T tile into QVls: wave w -> dtiles {2w, 2w+1}
#pragma unroll
        for (int i = 0; i < 2; ++i) {
            const int dt = wave * 2 + i;
            const __bf16* Vg = Vt + ((size_t)g * HD + dt * 16 + fr) * S_LEN + kt * 64;
#pragma unroll
            for (int ks = 0; ks < 2; ++ks)
                load16_to_lds(Vg + ks * 32 + fq * 8, &QVls[(size_t)((dt * 2 + ks) * 64) * 8]);
        }
        __syncthreads();   // staging complete

        // ---- QK^T ----
        f32x4 s_acc[4];
#pragma unroll
        for (int u = 0; u < 4; ++u) s_acc[u] = (f32x4){0.f, 0.f, 0.f, 0.f};
#pragma unroll
        for (int u = 0; u < 4; ++u)
#pragma unroll
            for (int ks = 0; ks < 4; ++ks)
                s_acc[u] = __builtin_amdgcn_mfma_f32_16x16x32_bf16(
                               aq[ks],
                               *(const bf16x8*)&Kls[((u * 4 + ks) * 64 + lane) * 8],
                               s_acc[u], 0, 0, 0);

        // ---- causal mask (diagonal tile only) ----
        if (kt == kt_max) {
#pragma unroll
            for (int u = 0; u < 4; ++u)
#pragma unroll
                for (int r = 0; r < 4; ++r)
                    if (kt * 64 + u * 16 + fr > q0 + wave * 16 + fq * 4 + r)
                        s_acc[u][r] = -INFINITY;
        }

        // ---- online softmax (row = fq*4+r; reduce over quad's 16 lanes) ----
#pragma unroll
        for (int r = 0; r < 4; ++r) {
            float mx = fmaxf(fmaxf(s_acc[0][r], s_acc[1][r]),
                             fmaxf(s_acc[2][r], s_acc[3][r]));
#pragma unroll
            for (int off = 1; off < 16; off <<= 1)
                mx = fmaxf(mx, __shfl_xor(mx, off));
            const float m_new = fmaxf(m_i[r], mx);
            const float alpha = exp2f(m_i[r] - m_new);
            m_i[r] = m_new;

            float p[4], psum = 0.0f;
#pragma unroll
            for (int u = 0; u < 4; ++u) {
                p[u] = exp2f(s_acc[u][r] - m_new);
                psum += p[u];
            }
#pragma unroll
            for (int off = 1; off < 16; off <<= 1)
                psum += __shfl_xor(psum, off);
            l_i[r] = l_i[r] * alpha + psum;

#pragma unroll
            for (int dt = 0; dt < 8; ++dt) o_acc[dt][r] *= alpha;

#pragma unroll
            for (int u = 0; u < 4; ++u) {
                const int k = u * 16 + fr;
                const int m = fq * 4 + r;
                const int idx = ((wave * 2 + (k >> 5)) * 64 + ((k >> 3) & 3) * 16 + m) * 8
                                + (k & 7);
                ((u16*)Pls)[idx] = f2bf(p[u]);
            }
        }

        // ---- PV (same-wave LDS write->read ordered) ----
        bf16x8 ap[2];
#pragma unroll
        for (int ks = 0; ks < 2; ++ks)
            ap[ks] = *(const bf16x8*)&Pls[((wave * 2 + ks) * 64 + lane) * 8];
#pragma unroll
        for (int dt = 0; dt < 8; ++dt)
#pragma unroll
            for (int ks = 0; ks < 2; ++ks)
                o_acc[dt] = __builtin_amdgcn_mfma_f32_16x16x32_bf16(
                                ap[ks],
                                *(const bf16x8*)&QVls[((dt * 2 + ks) * 64 + lane) * 8],
                                o_acc[dt], 0, 0, 0);
    }

    // ---- epilogue ----
#pragma unroll
    for (int r = 0; r < 4; ++r) {
        const float inv_l = 1.0f / l_i[r];
        const int s = q0 + wave * 16 + fq * 4 + r;
#pragma unroll
        for (int dt = 0; dt < 8; ++dt)
            Ob[(size_t)s * QKDIM + h * HD + dt * 16 + fr] = f2bf(o_acc[dt][r] * inv_l);
    }
}

// ---------------------------------------------------------------------------
extern "C" void kernel_launch(void* const* d_in, const int* in_sizes, int n_in,
                              void* d_out, int out_size, void* d_ws, size_t ws_size,
                              hipStream_t stream) {
    const float* x  = (const float*)d_in[0];
    const float* Wq = (const float*)d_in[1];
    const float* Wk = (const float*)d_in[2];
    const float* Wv = (const float*)d_in[3];
    const float* Wo = (const float*)d_in[4];
    const float* qw = (const float*)d_in[5];
    const float* kw = (const float*)d_in[6];

    float* out     = (float*)d_out;
    float* cache_k = out + (size_t)S_LEN * DMODEL;
    float* cache_v = cache_k + (size_t)NKV * S_LEN * HD;

    // ws layout (20M floats = 80 MB, same proven footprint):
    //   qg  [2048][4096]  8M floats   \_ QKV GEMM outputs (dead after
    //   kv  [2048][2048]  4M floats   /  norm_rope + v_transpose)
    //   rg  region R      8M floats
    float* ws = (float*)d_ws;
    float* qg = ws;
    float* kv = qg + (size_t)S_LEN * QKDIM;
    float* rg = kv + (size_t)S_LEN * KVCAT;

    // region R phase A (converts + QKV GEMM): bf16 weights, contiguous
    u16* Wqb = (u16*)rg;                              // 10.49M u16
    u16* Wkb = Wqb + (size_t)QKDIM * DMODEL;          //  2.62M
    u16* Wvb = Wkb + (size_t)KVDIM * DMODEL;          //  2.62M (15.73M u16 total)
    // region R phase B (norm/attention): bf16 Q, K, V^T + rope tables
    u16* qrb = (u16*)rg;                              //  8.39M u16
    u16* kcb = qrb + (size_t)NHEADS * S_LEN * HD;     //  2.10M
    u16* vtb = kcb + (size_t)NKV * S_LEN * HD;        //  2.10M (12.58M u16)
    float* ct = rg + (size_t)6400 * 1024;             // offset 6.55M floats
    float* st = ct + S_LEN * 64;                      // +131K  (ends 6.82M <= 8M)
    // qkv region phase C (dead after v_transpose): attn out bf16 + Wo bf16
    u16* aob = (u16*)qg;                              //  8.39M u16
    u16* Wob = aob + (size_t)S_LEN * QKDIM;           // 10.49M u16 (18.87M <= 24M)
    // x bf16 in d_out's out region (overwritten only by final GEMM)
    u16* xb  = (u16*)out;

    // 1) converts
    f32_to_bf16_k<<<1024, 256, 0, stream>>>(x,  xb,  S_LEN * DMODEL / 4);
    f32_to_bf16_k<<<1024, 256, 0, stream>>>(Wq, Wqb, QKDIM * DMODEL / 4);
    f32_to_bf16_k<<<1024, 256, 0, stream>>>(Wk, Wkb, KVDIM * DMODEL / 4);
    f32_to_bf16_k<<<1024, 256, 0, stream>>>(Wv, Wvb, KVDIM * DMODEL / 4);

    // 2) fused QKV projection
    gemm_qkv<<<dim3((QKDIM + KVCAT)/128, S_LEN/128), 256, 0, stream>>>(
        (const __bf16*)xb, (const __bf16*)Wqb, (const __bf16*)Wkb, qg, kv);

    // 3) rope tables + RMSNorm/RoPE
    rope_table<<<S_LEN, 64, 0, stream>>>(ct, st);
    norm_rope<<<dim3(NHEADS + NKV, S_LEN), 128, 0, stream>>>(
        qg, kv, ct, st, qw, kw, qrb, cache_k, kcb, cache_v);

    // 4) V^T bf16
    v_transpose<<<dim3(NKV, S_LEN/64, HD/64), 256, 0, stream>>>(kv, vtb);

    // 5) Wo convert (qkv region now dead) + MFMA flash attention
    f32_to_bf16_k<<<1024, 256, 0, stream>>>(Wo, Wob, DMODEL * QKDIM / 4);
    attn_mfma<<<dim3(S_LEN/64, NHEADS), 256, 0, stream>>>(
        (const __bf16*)qrb, (const __bf16*)kcb, (const __bf16*)vtb, aob);

    // 6) output projection
    gemm_bf16_nt<<<dim3(DMODEL/128, S_LEN/128), 256, 0, stream>>>(
        (const __bf16*)aob, (const __bf16*)Wob, out, S_LEN, DMODEL, QKDIM);
}